// Round 4
// baseline (2098.028 us; speedup 1.0000x reference)
//
#include <hip/hip_runtime.h>
#include <math.h>

#define D      256
#define K      16384
#define NPTS   8192
#define DELTA  0.2f
#define CAP    2000000u

// d_out layout (all f32): zq[8,256,32,32] | indices[8192] | bit[8,32,32,256] | loss[1]
#define O_IDX  2097152
#define O_BIT  2105344
#define O_LOSS 4202496

typedef __attribute__((ext_vector_type(8))) short bf16x8;
typedef __attribute__((ext_vector_type(4))) float f32x4;
typedef unsigned long long u64;

__device__ __forceinline__ unsigned f2s(float f) {
    unsigned u = __float_as_uint(f);
    return (u & 0x80000000u) ? ~u : (u | 0x80000000u);
}
__device__ __forceinline__ float s2f(unsigned s) {
    return __uint_as_float((s & 0x80000000u) ? (s & 0x7fffffffu) : ~s);
}
__device__ __forceinline__ unsigned short f2bf(float f) {  // RNE
    unsigned u = __float_as_uint(f);
    u += 0x7fffu + ((u >> 16) & 1u);
    return (unsigned short)(u >> 16);
}
__device__ __forceinline__ void gl2lds16(const unsigned short* g, unsigned short* l) {
    __builtin_amdgcn_global_load_lds(
        (const __attribute__((address_space(1))) void*)g,
        (__attribute__((address_space(3))) void*)l, 16, 0, 0);
}

// ---- zero argmax state ----
__global__ void init_state(unsigned* __restrict__ gmax, u64* __restrict__ keys,
                           unsigned* __restrict__ cnt) {
    const int i = blockIdx.x * 256 + threadIdx.x;
    gmax[i] = 0u;
    keys[i] = 0ull;
    if (i == 0) cnt[0] = 0u;
}

// ---- codebook: row norms (den) + bf16 normalized copy ----
__global__ __launch_bounds__(256) void prep_codebook(const float* __restrict__ E,
                                                     float* __restrict__ den,
                                                     unsigned short* __restrict__ ewb) {
    const int tid = threadIdx.x, lane = tid & 63, wave = tid >> 6;
    #pragma unroll
    for (int j = 0; j < 8; ++j) {
        const int row = blockIdx.x * 32 + wave * 8 + j;
        const float4 v = *(const float4*)(E + (size_t)row * D + lane * 4);
        float ss = v.x * v.x + v.y * v.y + v.z * v.z + v.w * v.w;
        #pragma unroll
        for (int o = 1; o < 64; o <<= 1) ss += __shfl_xor(ss, o);
        const float dn = fmaxf(sqrtf(ss), 1e-12f);
        const unsigned lo = (unsigned)f2bf(v.x / dn) | ((unsigned)f2bf(v.y / dn) << 16);
        const unsigned hi = (unsigned)f2bf(v.z / dn) | ((unsigned)f2bf(v.w / dn) << 16);
        *(uint2*)(ewb + (size_t)row * D + lane * 4) = make_uint2(lo, hi);
        if (lane == 0) den[row] = dn;
    }
}

// ---- z [8,256,1024] -> zfb [8192,256] bf16 ----
__global__ __launch_bounds__(256) void prep_z(const float* __restrict__ z,
                                              unsigned short* __restrict__ zfb) {
    const int bi = blockIdx.x, tid = threadIdx.x;
    const int b = bi >> 4, hw0 = (bi & 15) * 64;
    __shared__ float t[64][65];
    for (int dc = 0; dc < D; dc += 64) {
        #pragma unroll
        for (int it = 0; it < 16; ++it) {
            const int idx = it * 256 + tid;
            const int dl = idx >> 6, hw = idx & 63;
            t[dl][hw] = z[(size_t)(b * 256 + dc + dl) * 1024 + hw0 + hw];
        }
        __syncthreads();
        #pragma unroll
        for (int it = 0; it < 16; ++it) {
            const int idx = it * 256 + tid;
            const int pl = idx >> 6, dl = idx & 63;
            zfb[(size_t)(b * 1024 + hw0 + pl) * D + dc + dl] = f2bf(t[dl][pl]);
        }
        __syncthreads();
    }
}

// ---- phase 1: bf16 MFMA, per-point bf16 max, deferred candidate append ----
// grid (64 m, 16 n); block 256; per block: 128 points x 1024 codes
__global__ __launch_bounds__(256, 2) void score(const unsigned short* __restrict__ zfb,
                                                const unsigned short* __restrict__ ewb,
                                                unsigned* __restrict__ gmaxu,
                                                u64* __restrict__ cand,
                                                unsigned* __restrict__ cnt) {
    __shared__ __align__(16) unsigned short za[8 * 128 * 32];  // 64 KB: [chunk][row][32]
    __shared__ unsigned smax_l[128];
    __shared__ unsigned runu[128];
    __shared__ float thr[128];

    const int tid  = threadIdx.x;
    const int lane = tid & 63, wave = tid >> 6;
    const int quad = lane >> 4, col = lane & 15;
    const int wm   = wave >> 1, wn = wave & 1;
    const int m0   = blockIdx.x * 128;
    const int n0   = blockIdx.y * 1024;

    if (tid < 128) { smax_l[tid] = 0u; runu[tid] = 0u; }

    // stage A (128 rows x 256 shorts) once: [chunk c][row][4x16B slots]
    {
        const unsigned short* srcA = zfb + (size_t)m0 * D;
        #pragma unroll
        for (int i = 0; i < 16; ++i) {
            const int c = i >> 1, h = i & 1;
            const int r0 = wave * 32 + h * 16;
            const unsigned short* g = srcA + (size_t)(r0 + (lane >> 2)) * D + c * 32 + (lane & 3) * 8;
            unsigned short* l = &za[c * 4096 + r0 * 32];
            gl2lds16(g, l);
        }
    }
    __syncthreads();

    for (int sub = 0; sub < 8; ++sub) {
        const unsigned short* Bb = ewb + (size_t)(n0 + sub * 128 + wn * 64) * D;
        f32x4 acc[4][4];
        #pragma unroll
        for (int i = 0; i < 4; ++i)
            #pragma unroll
            for (int j = 0; j < 4; ++j)
                acc[i][j] = (f32x4){0.f, 0.f, 0.f, 0.f};

        #pragma unroll
        for (int c = 0; c < 8; ++c) {
            bf16x8 af[4], bf[4];
            #pragma unroll
            for (int mt = 0; mt < 4; ++mt)
                af[mt] = *(const bf16x8*)&za[c * 4096 + (wm * 64 + mt * 16 + col) * 32 + quad * 8];
            #pragma unroll
            for (int nt = 0; nt < 4; ++nt)
                bf[nt] = *(const bf16x8*)(Bb + (size_t)(nt * 16 + col) * D + c * 32 + quad * 8);
            #pragma unroll
            for (int mt = 0; mt < 4; ++mt)
                #pragma unroll
                for (int nt = 0; nt < 4; ++nt)
                    acc[mt][nt] = __builtin_amdgcn_mfma_f32_16x16x32_bf16(af[mt], bf[nt],
                                                                          acc[mt][nt], 0, 0, 0);
        }

        // local per-point max over 4 nt, then over 16 cols
        float pmL[4][4], red[4][4];
        #pragma unroll
        for (int mt = 0; mt < 4; ++mt)
            #pragma unroll
            for (int r = 0; r < 4; ++r) {
                pmL[mt][r] = fmaxf(fmaxf(acc[mt][0][r], acc[mt][1][r]),
                                   fmaxf(acc[mt][2][r], acc[mt][3][r]));
                red[mt][r] = pmL[mt][r];
            }
        #pragma unroll
        for (int off = 1; off < 16; off <<= 1)
            #pragma unroll
            for (int mt = 0; mt < 4; ++mt)
                #pragma unroll
                for (int r = 0; r < 4; ++r)
                    red[mt][r] = fmaxf(red[mt][r], __shfl_xor(red[mt][r], off));
        if (col == 0) {
            #pragma unroll
            for (int mt = 0; mt < 4; ++mt)
                #pragma unroll
                for (int r = 0; r < 4; ++r)
                    atomicMax(&smax_l[wm * 64 + mt * 16 + quad * 4 + r], f2s(red[mt][r]));
        }
        __syncthreads();
        if (tid < 128) {
            unsigned ru = runu[tid], sm = smax_l[tid];
            ru = (sm > ru) ? sm : ru;
            runu[tid] = ru;
            smax_l[tid] = 0u;
            const unsigned g = *(volatile const unsigned*)&gmaxu[m0 + tid];
            thr[tid] = s2f(g > ru ? g : ru) - DELTA;
        }
        __syncthreads();

        // append candidates >= thr
        #pragma unroll
        for (int mt = 0; mt < 4; ++mt) {
            #pragma unroll
            for (int r = 0; r < 4; ++r) {
                const int pl = wm * 64 + mt * 16 + quad * 4 + r;
                const float tp = thr[pl];
                if (pmL[mt][r] >= tp) {
                    #pragma unroll
                    for (int nt = 0; nt < 4; ++nt) {
                        const float v = acc[mt][nt][r];
                        if (v >= tp) {
                            const unsigned idx = atomicAdd(cnt, 1u);
                            if (idx < CAP) {
                                const unsigned pc = ((unsigned)(m0 + pl) << 14) |
                                                    (unsigned)(n0 + sub * 128 + wn * 64 + nt * 16 + col);
                                cand[idx] = ((u64)pc << 32) | __float_as_uint(v);
                            }
                        }
                    }
                }
            }
        }
        if ((sub == 0 || sub == 7) && tid < 128)
            atomicMax(&gmaxu[m0 + tid], runu[tid]);
    }
}

// ---- phase 2: filter vs final gmax, exact fp32 rescore (one wave per candidate) ----
__global__ __launch_bounds__(256) void resolve(const float* __restrict__ z,
                                               const float* __restrict__ E,
                                               const float* __restrict__ den,
                                               const unsigned* __restrict__ gmaxu,
                                               const u64* __restrict__ cand,
                                               const unsigned* __restrict__ cnt,
                                               u64* __restrict__ keys) {
    const unsigned total = min(cnt[0], CAP);
    const int lane = threadIdx.x & 63;
    const unsigned wglob = (blockIdx.x * 256 + threadIdx.x) >> 6;
    const unsigned nw = gridDim.x * 4;
    for (unsigned i = wglob; i < total; i += nw) {
        const u64 e = cand[i];
        const unsigned pc = (unsigned)(e >> 32);
        const float s = __uint_as_float((unsigned)(e & 0xffffffffull));
        const int p = pc >> 14, c = pc & 16383;
        if (s < s2f(gmaxu[p]) - DELTA) continue;
        const int b = p >> 10, hw = p & 1023;
        const float d = den[c];
        const float4 bv = *(const float4*)(E + (size_t)c * D + lane * 4);
        const float z0 = z[(size_t)(b * 256 + lane * 4 + 0) * 1024 + hw];
        const float z1 = z[(size_t)(b * 256 + lane * 4 + 1) * 1024 + hw];
        const float z2 = z[(size_t)(b * 256 + lane * 4 + 2) * 1024 + hw];
        const float z3 = z[(size_t)(b * 256 + lane * 4 + 3) * 1024 + hw];
        float sv = fmaf(z0, bv.x / d, fmaf(z1, bv.y / d, fmaf(z2, bv.z / d, z3 * (bv.w / d))));
        #pragma unroll
        for (int o = 1; o < 64; o <<= 1) sv += __shfl_xor(sv, o);
        if (lane == 0)
            atomicMax(keys + p, ((u64)f2s(sv) << 32) | (unsigned)(16383 - c));
    }
}

// ---- gather + outputs ----
__global__ __launch_bounds__(256) void finalize(const float* __restrict__ E,
                                                const float* __restrict__ den,
                                                const u64* __restrict__ keys,
                                                float* __restrict__ out) {
    const int n = blockIdx.x, tid = threadIdx.x;
    const u64 key = keys[n];
    const int idx = 16383 - (int)(unsigned)(key & 0xffffffffull);
    const float v = E[(size_t)idx * D + tid] / den[idx];
    const int b = n >> 10, off = n & 1023;
    out[(size_t)(b * D + tid) * 1024 + off] = v;
    const float S = 5.65685424949238019520675489683895f;  // sqrt(32)
    out[O_BIT + (size_t)n * D + tid] = (float)((int)(v * S) + 4);
    if (tid == 0) out[O_IDX + n] = (float)idx;
    if (n == 0 && tid == 0) out[O_LOSS] = 0.0f;
}

extern "C" void kernel_launch(void* const* d_in, const int* in_sizes, int n_in,
                              void* d_out, int out_size, void* d_ws, size_t ws_size,
                              hipStream_t stream) {
    const float* z = (const float*)d_in[0];
    const float* E = (const float*)d_in[1];
    float* out = (float*)d_out;

    char* w = (char*)d_ws;
    u64*            cand = (u64*)w;                       w += (size_t)CAP * 8;   // 16 MB
    unsigned short* ewb  = (unsigned short*)w;            w += (size_t)K * D * 2; //  8 MB
    unsigned short* zfb  = (unsigned short*)w;            w += (size_t)NPTS * D * 2; // 4 MB
    u64*            keys = (u64*)w;                       w += (size_t)NPTS * 8;  // 64 KB
    float*          den  = (float*)w;                     w += (size_t)K * 4;     // 64 KB
    unsigned*       gmax = (unsigned*)w;                  w += (size_t)NPTS * 4;  // 32 KB
    unsigned*       cnt  = (unsigned*)w;

    init_state<<<NPTS / 256, 256, 0, stream>>>(gmax, keys, cnt);
    prep_codebook<<<K / 32, 256, 0, stream>>>(E, den, ewb);
    prep_z<<<128, 256, 0, stream>>>(z, zfb);

    dim3 g1(NPTS / 128, K / 1024);
    score<<<g1, 256, 0, stream>>>(zfb, ewb, gmax, cand, cnt);

    resolve<<<256, 256, 0, stream>>>(z, E, den, gmax, cand, cnt, keys);
    finalize<<<NPTS, 256, 0, stream>>>(E, den, keys, out);
}

// Round 5
// 1068.882 us; speedup vs baseline: 1.9628x; 1.9628x over previous
//
#include <hip/hip_runtime.h>
#include <math.h>

#define D      256
#define K      16384
#define NPTS   8192
#define DELTA  0.2f
#define CAP    1700000u
#define CAP2   200000u

// d_out layout (all f32): zq[8,256,32,32] | indices[8192] | bit[8,32,32,256] | loss[1]
#define O_IDX  2097152
#define O_BIT  2105344
#define O_LOSS 4202496

typedef __attribute__((ext_vector_type(8))) short bf16x8;
typedef __attribute__((ext_vector_type(4))) float f32x4;
typedef unsigned long long u64;

__device__ __forceinline__ unsigned f2s(float f) {
    unsigned u = __float_as_uint(f);
    return (u & 0x80000000u) ? ~u : (u | 0x80000000u);
}
__device__ __forceinline__ float s2f(unsigned s) {
    return __uint_as_float((s & 0x80000000u) ? (s & 0x7fffffffu) : ~s);
}
__device__ __forceinline__ unsigned short f2bf(float f) {  // RNE
    unsigned u = __float_as_uint(f);
    u += 0x7fffu + ((u >> 16) & 1u);
    return (unsigned short)(u >> 16);
}
__device__ __forceinline__ void gl2lds16(const unsigned short* g, unsigned short* l) {
    __builtin_amdgcn_global_load_lds(
        (const __attribute__((address_space(1))) void*)g,
        (__attribute__((address_space(3))) void*)l, 16, 0, 0);
}

__global__ void init_state(unsigned* __restrict__ gmax, u64* __restrict__ keys,
                           unsigned* __restrict__ cnt) {
    const int i = blockIdx.x * 256 + threadIdx.x;
    gmax[i] = 0u;
    keys[i] = 0ull;
    if (i < 2) cnt[i] = 0u;
}

// ---- codebook: row norms (den) + bf16 normalized copy ----
__global__ __launch_bounds__(256) void prep_codebook(const float* __restrict__ E,
                                                     float* __restrict__ den,
                                                     unsigned short* __restrict__ ewb) {
    const int tid = threadIdx.x, lane = tid & 63, wave = tid >> 6;
    #pragma unroll
    for (int j = 0; j < 8; ++j) {
        const int row = blockIdx.x * 32 + wave * 8 + j;
        const float4 v = *(const float4*)(E + (size_t)row * D + lane * 4);
        float ss = v.x * v.x + v.y * v.y + v.z * v.z + v.w * v.w;
        #pragma unroll
        for (int o = 1; o < 64; o <<= 1) ss += __shfl_xor(ss, o);
        const float dn = fmaxf(sqrtf(ss), 1e-12f);
        const unsigned lo = (unsigned)f2bf(v.x / dn) | ((unsigned)f2bf(v.y / dn) << 16);
        const unsigned hi = (unsigned)f2bf(v.z / dn) | ((unsigned)f2bf(v.w / dn) << 16);
        *(uint2*)(ewb + (size_t)row * D + lane * 4) = make_uint2(lo, hi);
        if (lane == 0) den[row] = dn;
    }
}

// ---- z [8,256,1024] -> zfb/zf32 [8192,256] ----
__global__ __launch_bounds__(256) void prep_z(const float* __restrict__ z,
                                              unsigned short* __restrict__ zfb,
                                              float* __restrict__ zf32) {
    const int bi = blockIdx.x, tid = threadIdx.x;
    const int b = bi >> 4, hw0 = (bi & 15) * 64;
    __shared__ float t[64][65];
    for (int dc = 0; dc < D; dc += 64) {
        #pragma unroll
        for (int it = 0; it < 16; ++it) {
            const int idx = it * 256 + tid;
            const int dl = idx >> 6, hw = idx & 63;
            t[dl][hw] = z[(size_t)(b * 256 + dc + dl) * 1024 + hw0 + hw];
        }
        __syncthreads();
        #pragma unroll
        for (int it = 0; it < 16; ++it) {
            const int idx = it * 256 + tid;
            const int pl = idx >> 6, dl = idx & 63;
            const float v = t[dl][pl];
            const size_t o = (size_t)(b * 1024 + hw0 + pl) * D + dc + dl;
            zfb[o]  = f2bf(v);
            zf32[o] = v;
        }
        __syncthreads();
    }
}

// ---- phase 1: MFMA scores, per-point bf16 max, ballot-aggregated candidate append ----
// grid (NPTS/128, K/1024); block 512 (8 waves); per block: 128 pts x 1024 codes
// wave tile 32m x 64n; A (128x256) LDS-resident; B per 32-chunk via global_load_lds
__global__ __launch_bounds__(512, 4) void score(const unsigned short* __restrict__ zfb,
                                                const unsigned short* __restrict__ ewb,
                                                unsigned* __restrict__ gmaxu,
                                                u64* __restrict__ cand,
                                                unsigned* __restrict__ cnt) {
    __shared__ __align__(16) unsigned short za[8 * 128 * 32];  // 64 KB: [chunk][row][32]
    __shared__ __align__(16) unsigned short bb[128 * 32];      //  8 KB: [row][32]
    __shared__ unsigned smax_l[128];
    __shared__ unsigned runu[128];
    __shared__ float thr[128];

    const int tid  = threadIdx.x;
    const int lane = tid & 63, wave = tid >> 6;         // 8 waves
    const int quad = lane >> 4, col = lane & 15;
    const int wm   = wave >> 1, wn = wave & 1;          // 4 x 2 wave grid
    const int m0   = blockIdx.x * 128;
    const int n0   = blockIdx.y * 1024;

    if (tid < 128) { smax_l[tid] = 0u; runu[tid] = 0u; }

    const int srow = lane >> 2, schk = (lane & 3) * 8;  // 16 rows x 64B per wave-instr

    // stage A once: za[c][row][32]
    {
        const unsigned short* gA = zfb + (size_t)(m0 + wave * 16 + srow) * D + schk;
        unsigned short* lA = &za[(wave * 16) * 32];
        #pragma unroll
        for (int c = 0; c < 8; ++c)
            gl2lds16(gA + c * 32, lA + c * 4096);
    }

    for (int sub = 0; sub < 8; ++sub) {
        const unsigned short* gB = ewb + (size_t)(n0 + sub * 128 + wave * 16 + srow) * D + schk;
        unsigned short* lB = &bb[(wave * 16) * 32];

        f32x4 acc[2][4];
        #pragma unroll
        for (int i = 0; i < 2; ++i)
            #pragma unroll
            for (int j = 0; j < 4; ++j)
                acc[i][j] = (f32x4){0.f, 0.f, 0.f, 0.f};

        for (int c = 0; c < 8; ++c) {
            __syncthreads();                 // bb safe to overwrite
            gl2lds16(gB + c * 32, lB);       // 1 instr/wave
            __syncthreads();                 // drain: bb (and A on first iter) ready
            bf16x8 af[2], bf[4];
            #pragma unroll
            for (int mt = 0; mt < 2; ++mt)
                af[mt] = *(const bf16x8*)&za[c * 4096 + (wm * 32 + mt * 16 + col) * 32 + quad * 8];
            #pragma unroll
            for (int nt = 0; nt < 4; ++nt)
                bf[nt] = *(const bf16x8*)&bb[(wn * 64 + nt * 16 + col) * 32 + quad * 8];
            #pragma unroll
            for (int mt = 0; mt < 2; ++mt)
                #pragma unroll
                for (int nt = 0; nt < 4; ++nt)
                    acc[mt][nt] = __builtin_amdgcn_mfma_f32_16x16x32_bf16(af[mt], bf[nt],
                                                                          acc[mt][nt], 0, 0, 0);
        }

        // per-point max over this sub's 128 codes
        float pmL[2][4], red[2][4];
        #pragma unroll
        for (int mt = 0; mt < 2; ++mt)
            #pragma unroll
            for (int r = 0; r < 4; ++r) {
                pmL[mt][r] = fmaxf(fmaxf(acc[mt][0][r], acc[mt][1][r]),
                                   fmaxf(acc[mt][2][r], acc[mt][3][r]));
                red[mt][r] = pmL[mt][r];
            }
        #pragma unroll
        for (int off = 1; off < 16; off <<= 1)
            #pragma unroll
            for (int mt = 0; mt < 2; ++mt)
                #pragma unroll
                for (int r = 0; r < 4; ++r)
                    red[mt][r] = fmaxf(red[mt][r], __shfl_xor(red[mt][r], off));
        if (col == 0) {
            #pragma unroll
            for (int mt = 0; mt < 2; ++mt)
                #pragma unroll
                for (int r = 0; r < 4; ++r)
                    atomicMax(&smax_l[wm * 32 + mt * 16 + quad * 4 + r], f2s(red[mt][r]));
        }
        __syncthreads();
        if (tid < 128) {
            const unsigned sm = smax_l[tid];
            smax_l[tid] = 0u;
            unsigned ru = runu[tid];
            ru = (sm > ru) ? sm : ru;
            runu[tid] = ru;
            const unsigned old = atomicMax(&gmaxu[m0 + tid], ru);  // update + peek
            thr[tid] = s2f(old > ru ? old : ru) - DELTA;
        }
        __syncthreads();

        // ballot-aggregated append of near-max candidates
        #pragma unroll
        for (int mt = 0; mt < 2; ++mt) {
            #pragma unroll
            for (int r = 0; r < 4; ++r) {
                const int pl   = wm * 32 + mt * 16 + quad * 4 + r;
                const float tp = thr[pl];
                #pragma unroll
                for (int nt = 0; nt < 4; ++nt) {
                    const float v = acc[mt][nt][r];
                    const bool pred = (v >= tp);
                    const u64 mask = __ballot(pred);
                    if (mask) {
                        const int lead = __ffsll((long long)mask) - 1;
                        unsigned base = 0;
                        if (lane == lead) base = atomicAdd(cnt, (unsigned)__popcll(mask));
                        base = __shfl(base, lead);
                        if (pred) {
                            const unsigned slot = base +
                                (unsigned)__popcll(mask & ((1ull << lane) - 1ull));
                            if (slot < CAP) {
                                const unsigned code = n0 + sub * 128 + wn * 64 + nt * 16 + col;
                                const unsigned pc = ((unsigned)(m0 + pl) << 14) | code;
                                cand[slot] = ((u64)pc << 32) | __float_as_uint(v);
                            }
                        }
                    }
                }
            }
        }
    }
}

// ---- phase 2a: thread-level filter vs FINAL gmax -> survivors ----
__global__ __launch_bounds__(256) void resolve_filter(const unsigned* __restrict__ gmaxu,
                                                      const u64* __restrict__ cand,
                                                      const unsigned* __restrict__ cnt,
                                                      u64* __restrict__ cand2,
                                                      unsigned* __restrict__ cnt2) {
    const unsigned total = min(cnt[0], CAP);
    const int lane = threadIdx.x & 63;
    const unsigned stride = gridDim.x * 256;
    for (unsigned base = blockIdx.x * 256; base < total; base += stride) {
        const unsigned i = base + threadIdx.x;
        bool keep = false;
        u64 e = 0;
        if (i < total) {
            e = cand[i];
            const int p = (int)(e >> 46);
            const float s = __uint_as_float((unsigned)(e & 0xffffffffull));
            keep = (s >= s2f(gmaxu[p]) - DELTA);
        }
        const u64 mask = __ballot(keep);
        if (mask) {
            const int lead = __ffsll((long long)mask) - 1;
            unsigned b2 = 0;
            if (lane == lead) b2 = atomicAdd(cnt2, (unsigned)__popcll(mask));
            b2 = __shfl(b2, lead);
            if (keep) {
                const unsigned slot = b2 + (unsigned)__popcll(mask & ((1ull << lane) - 1ull));
                if (slot < CAP2) cand2[slot] = e;
            }
        }
    }
}

// ---- phase 2b: wave-per-survivor exact fp32 rescore ----
__global__ __launch_bounds__(256) void rescore(const float* __restrict__ zf32,
                                               const float* __restrict__ E,
                                               const float* __restrict__ den,
                                               const u64* __restrict__ cand2,
                                               const unsigned* __restrict__ cnt2,
                                               u64* __restrict__ keys) {
    const unsigned total = min(cnt2[0], CAP2);
    const int lane = threadIdx.x & 63;
    const unsigned w = (blockIdx.x * 256 + threadIdx.x) >> 6;
    const unsigned nw = gridDim.x * 4;
    for (unsigned i = w; i < total; i += nw) {
        const u64 e = cand2[i];
        const unsigned pc = (unsigned)(e >> 32);
        const int p = pc >> 14, c = pc & 16383;
        const float dinv = 1.0f / den[c];
        const float4 a = *(const float4*)(zf32 + (size_t)p * D + lane * 4);
        const float4 b = *(const float4*)(E + (size_t)c * D + lane * 4);
        float sv = fmaf(a.x, b.x * dinv, fmaf(a.y, b.y * dinv,
                   fmaf(a.z, b.z * dinv, a.w * (b.w * dinv))));
        #pragma unroll
        for (int o = 1; o < 64; o <<= 1) sv += __shfl_xor(sv, o);
        if (lane == 0)
            atomicMax(keys + p, ((u64)f2s(sv) << 32) | (unsigned)(16383 - c));
    }
}

// ---- gather + outputs ----
__global__ __launch_bounds__(256) void finalize(const float* __restrict__ E,
                                                const float* __restrict__ den,
                                                const u64* __restrict__ keys,
                                                float* __restrict__ out) {
    const int n = blockIdx.x, tid = threadIdx.x;
    const u64 key = keys[n];
    const int idx = 16383 - (int)(unsigned)(key & 0xffffffffull);
    const float v = E[(size_t)idx * D + tid] / den[idx];
    const int b = n >> 10, off = n & 1023;
    out[(size_t)(b * D + tid) * 1024 + off] = v;
    const float S = 5.65685424949238019520675489683895f;  // sqrt(32)
    out[O_BIT + (size_t)n * D + tid] = (float)((int)(v * S) + 4);
    if (tid == 0) out[O_IDX + n] = (float)idx;
    if (n == 0 && tid == 0) out[O_LOSS] = 0.0f;
}

extern "C" void kernel_launch(void* const* d_in, const int* in_sizes, int n_in,
                              void* d_out, int out_size, void* d_ws, size_t ws_size,
                              hipStream_t stream) {
    const float* z = (const float*)d_in[0];
    const float* E = (const float*)d_in[1];
    float* out = (float*)d_out;

    char* w = (char*)d_ws;
    u64*            cand  = (u64*)w;             w += (size_t)CAP * 8;        // 13.6 MB
    u64*            cand2 = (u64*)w;             w += (size_t)CAP2 * 8;       //  1.6 MB
    unsigned short* ewb   = (unsigned short*)w;  w += (size_t)K * D * 2;      //  8 MB
    unsigned short* zfb   = (unsigned short*)w;  w += (size_t)NPTS * D * 2;   //  4 MB
    float*          zf32  = (float*)w;           w += (size_t)NPTS * D * 4;   //  8 MB
    u64*            keys  = (u64*)w;             w += (size_t)NPTS * 8;       // 64 KB
    float*          den   = (float*)w;           w += (size_t)K * 4;          // 64 KB
    unsigned*       gmax  = (unsigned*)w;        w += (size_t)NPTS * 4;       // 32 KB
    unsigned*       cnt   = (unsigned*)w;        // [0]=cand count, [1]=cand2 count

    init_state<<<NPTS / 256, 256, 0, stream>>>(gmax, keys, cnt);
    prep_codebook<<<K / 32, 256, 0, stream>>>(E, den, ewb);
    prep_z<<<128, 256, 0, stream>>>(z, zfb, zf32);

    dim3 g1(NPTS / 128, K / 1024);
    score<<<g1, 512, 0, stream>>>(zfb, ewb, gmax, cand, cnt);

    resolve_filter<<<128, 256, 0, stream>>>(gmax, cand, cnt, cand2, cnt + 1);
    rescore<<<256, 256, 0, stream>>>(zf32, E, den, cand2, cnt + 1, keys);
    finalize<<<NPTS, 256, 0, stream>>>(E, den, keys, out);
}

// Round 6
// 295.793 us; speedup vs baseline: 7.0929x; 3.6136x over previous
//
#include <hip/hip_runtime.h>
#include <math.h>

#define D      256
#define K      16384
#define NPTS   8192
#define DELTA  0.2f
#define CAP    1600000u
#define LCAP   1024

// d_out layout (all f32): zq[8,256,32,32] | indices[8192] | bit[8,32,32,256] | loss[1]
#define O_IDX  2097152
#define O_BIT  2105344
#define O_LOSS 4202496

typedef __attribute__((ext_vector_type(8))) short bf16x8;
typedef __attribute__((ext_vector_type(4))) float f32x4;
typedef unsigned long long u64;

__device__ __forceinline__ unsigned f2s(float f) {
    unsigned u = __float_as_uint(f);
    return (u & 0x80000000u) ? ~u : (u | 0x80000000u);
}
__device__ __forceinline__ float s2f(unsigned s) {
    return __uint_as_float((s & 0x80000000u) ? (s & 0x7fffffffu) : ~s);
}
__device__ __forceinline__ unsigned short f2bf(float f) {  // RNE
    unsigned u = __float_as_uint(f);
    u += 0x7fffu + ((u >> 16) & 1u);
    return (unsigned short)(u >> 16);
}
__device__ __forceinline__ void gl2lds16(const unsigned short* g, unsigned short* l) {
    __builtin_amdgcn_global_load_lds(
        (const __attribute__((address_space(1))) void*)g,
        (__attribute__((address_space(3))) void*)l, 16, 0, 0);
}

// ---- codebook norms + bf16 normalized copy; folds state init ----
__global__ __launch_bounds__(256) void prep_codebook(const float* __restrict__ E,
                                                     float* __restrict__ den,
                                                     unsigned short* __restrict__ ewb,
                                                     unsigned* __restrict__ gmax,
                                                     u64* __restrict__ keys,
                                                     unsigned* __restrict__ cnt) {
    const int tid = threadIdx.x, lane = tid & 63, wave = tid >> 6;
    const int b = blockIdx.x;
    if (b < 32)        gmax[b * 256 + tid] = 0u;
    else if (b < 64)   keys[(b - 32) * 256 + tid] = 0ull;
    else if (b == 64 && tid < 2) cnt[tid] = 0u;
    #pragma unroll
    for (int j = 0; j < 8; ++j) {
        const int row = b * 32 + wave * 8 + j;
        const float4 v = *(const float4*)(E + (size_t)row * D + lane * 4);
        float ss = v.x * v.x + v.y * v.y + v.z * v.z + v.w * v.w;
        #pragma unroll
        for (int o = 1; o < 64; o <<= 1) ss += __shfl_xor(ss, o);
        const float dn = fmaxf(sqrtf(ss), 1e-12f);
        const unsigned lo = (unsigned)f2bf(v.x / dn) | ((unsigned)f2bf(v.y / dn) << 16);
        const unsigned hi = (unsigned)f2bf(v.z / dn) | ((unsigned)f2bf(v.w / dn) << 16);
        *(uint2*)(ewb + (size_t)row * D + lane * 4) = make_uint2(lo, hi);
        if (lane == 0) den[row] = dn;
    }
}

// ---- z [8,256,1024] -> zfb/zf32 [8192,256] ----
__global__ __launch_bounds__(256) void prep_z(const float* __restrict__ z,
                                              unsigned short* __restrict__ zfb,
                                              float* __restrict__ zf32) {
    const int bi = blockIdx.x, tid = threadIdx.x;
    const int b = bi >> 4, hw0 = (bi & 15) * 64;
    __shared__ float t[64][65];
    for (int dc = 0; dc < D; dc += 64) {
        #pragma unroll
        for (int it = 0; it < 16; ++it) {
            const int idx = it * 256 + tid;
            const int dl = idx >> 6, hw = idx & 63;
            t[dl][hw] = z[(size_t)(b * 256 + dc + dl) * 1024 + hw0 + hw];
        }
        __syncthreads();
        #pragma unroll
        for (int it = 0; it < 16; ++it) {
            const int idx = it * 256 + tid;
            const int pl = idx >> 6, dl = idx & 63;
            const float v = t[dl][pl];
            const size_t o = (size_t)(b * 1024 + hw0 + pl) * D + dc + dl;
            zfb[o]  = f2bf(v);
            zf32[o] = v;
        }
        __syncthreads();
    }
}

// ================= shared GEMM macro body =================
// 4 waves, 2x2 wave grid, tile 128m x 128n, BK=32, 8 iters.
// Produces acc[4][4] (f32x4); point = m0+wm*64+mt*16+quad*4+r; code = n0+wn*64+nt*16+col.
#define GEMM_BODY(M0, N0)                                                          \
    f32x4 acc[4][4];                                                               \
    _Pragma("unroll")                                                              \
    for (int i = 0; i < 4; ++i)                                                    \
        _Pragma("unroll")                                                          \
        for (int j = 0; j < 4; ++j) acc[i][j] = (f32x4){0.f, 0.f, 0.f, 0.f};       \
    {                                                                              \
        const int srow = lane >> 2, schk = (lane & 3) * 8;                         \
        const unsigned short* gA = zfb + (size_t)((M0) + wave * 32 + srow) * D + schk; \
        const unsigned short* gB = ewb + (size_t)((N0) + wave * 32 + srow) * D + schk; \
        unsigned short* lA = &za[(wave * 32) * 32];                                \
        unsigned short* lB = &eb[(wave * 32) * 32];                                \
        for (int dc = 0; dc < D; dc += 32) {                                       \
            __syncthreads();                                                       \
            gl2lds16(gA + dc,          lA);                                        \
            gl2lds16(gA + dc + 16 * D, lA + 16 * 32);                              \
            gl2lds16(gB + dc,          lB);                                        \
            gl2lds16(gB + dc + 16 * D, lB + 16 * 32);                              \
            __syncthreads();                                                       \
            bf16x8 af[4], bfr[4];                                                  \
            _Pragma("unroll")                                                      \
            for (int mt = 0; mt < 4; ++mt)                                         \
                af[mt] = *(const bf16x8*)&za[(wm * 64 + mt * 16 + col) * 32 + quad * 8]; \
            _Pragma("unroll")                                                      \
            for (int nt = 0; nt < 4; ++nt)                                         \
                bfr[nt] = *(const bf16x8*)&eb[(wn * 64 + nt * 16 + col) * 32 + quad * 8]; \
            _Pragma("unroll")                                                      \
            for (int mt = 0; mt < 4; ++mt)                                         \
                _Pragma("unroll")                                                  \
                for (int nt = 0; nt < 4; ++nt)                                     \
                    acc[mt][nt] = __builtin_amdgcn_mfma_f32_16x16x32_bf16(af[mt], bfr[nt], \
                                                                          acc[mt][nt], 0, 0, 0); \
        }                                                                          \
    }

// ---- pre-pass: codes [0,2048), per-point seed max (atomicMax at block end only) ----
__global__ __launch_bounds__(256, 4) void pre_score(const unsigned short* __restrict__ zfb,
                                                    const unsigned short* __restrict__ ewb,
                                                    unsigned* __restrict__ gmax) {
    __shared__ __align__(16) unsigned short za[128 * 32];
    __shared__ __align__(16) unsigned short eb[128 * 32];
    const int tid = threadIdx.x, lane = tid & 63, wave = tid >> 6;
    const int quad = lane >> 4, col = lane & 15;
    const int wm = wave >> 1, wn = wave & 1;
    const int m0 = blockIdx.x * 128, n0 = blockIdx.y * 128;
    (void)wn;

    GEMM_BODY(m0, n0)

    #pragma unroll
    for (int mt = 0; mt < 4; ++mt) {
        #pragma unroll
        for (int r = 0; r < 4; ++r) {
            float pm = fmaxf(fmaxf(acc[mt][0][r], acc[mt][1][r]),
                             fmaxf(acc[mt][2][r], acc[mt][3][r]));
            #pragma unroll
            for (int off = 1; off < 16; off <<= 1)
                pm = fmaxf(pm, __shfl_xor(pm, off));
            if (col == 0)
                atomicMax(&gmax[m0 + wm * 64 + mt * 16 + quad * 4 + r], f2s(pm));
        }
    }
}

// ---- main score: pure GEMM + block-end LDS-buffered candidate append ----
__global__ __launch_bounds__(256, 4) void score(const unsigned short* __restrict__ zfb,
                                                const unsigned short* __restrict__ ewb,
                                                const unsigned* __restrict__ gmax,
                                                u64* __restrict__ cand,
                                                unsigned* __restrict__ cnt) {
    __shared__ __align__(16) unsigned short za[128 * 32];
    __shared__ __align__(16) unsigned short eb[128 * 32];
    __shared__ float thrL[128];
    __shared__ u64 lbuf[LCAP];
    __shared__ unsigned lcount, lbase;

    const int tid = threadIdx.x, lane = tid & 63, wave = tid >> 6;
    const int quad = lane >> 4, col = lane & 15;
    const int wm = wave >> 1, wn = wave & 1;
    const int m0 = blockIdx.x * 128, n0 = blockIdx.y * 128;

    if (tid < 128) thrL[tid] = s2f(gmax[m0 + tid]) - DELTA;   // seed threshold, loaded once
    if (tid == 0) lcount = 0u;
    // (first __syncthreads inside GEMM_BODY publishes these)

    GEMM_BODY(m0, n0)

    // epilogue: ballot -> LDS buffer append
    #pragma unroll
    for (int mt = 0; mt < 4; ++mt) {
        #pragma unroll
        for (int r = 0; r < 4; ++r) {
            const int pl = wm * 64 + mt * 16 + quad * 4 + r;
            const float tp = thrL[pl];
            #pragma unroll
            for (int nt = 0; nt < 4; ++nt) {
                const float v = acc[mt][nt][r];
                const bool pred = (v >= tp);
                const u64 mask = __ballot(pred);
                if (mask) {
                    const int lead = __ffsll((long long)mask) - 1;
                    unsigned base = 0;
                    if (lane == lead) base = atomicAdd(&lcount, (unsigned)__popcll(mask));
                    base = __shfl(base, lead);
                    if (pred) {
                        const unsigned slot = base +
                            (unsigned)__popcll(mask & ((1ull << lane) - 1ull));
                        const unsigned code = n0 + wn * 64 + nt * 16 + col;
                        const u64 e = ((u64)(((unsigned)(m0 + pl) << 14) | code) << 32) | f2s(v);
                        if (slot < LCAP) lbuf[slot] = e;
                        else {                       // rare overflow: direct global append
                            const unsigned g = atomicAdd(cnt, 1u);
                            if (g < CAP) cand[g] = e;
                        }
                    }
                }
            }
        }
    }
    __syncthreads();
    const unsigned m_ = lcount < LCAP ? lcount : LCAP;
    if (tid == 0) lbase = atomicAdd(cnt, m_);
    __syncthreads();
    for (unsigned i = tid; i < m_; i += 256) {
        const unsigned g = lbase + i;
        if (g < CAP) cand[g] = lbuf[i];
    }
}

// ---- final per-point bf16 max over candidates ----
__global__ __launch_bounds__(256) void cand_max(const u64* __restrict__ cand,
                                                const unsigned* __restrict__ cnt,
                                                unsigned* __restrict__ gmax) {
    const unsigned total = min(cnt[0], CAP);
    const unsigned stride = gridDim.x * 256;
    for (unsigned i = blockIdx.x * 256 + threadIdx.x; i < total; i += stride) {
        const u64 e = cand[i];
        atomicMax(&gmax[(unsigned)(e >> 46)], (unsigned)(e & 0xffffffffull));
    }
}

// ---- wave-per-candidate: filter vs final max, exact fp32 rescore ----
__global__ __launch_bounds__(256) void rescore(const float* __restrict__ zf32,
                                               const float* __restrict__ E,
                                               const float* __restrict__ den,
                                               const unsigned* __restrict__ gmax,
                                               const u64* __restrict__ cand,
                                               const unsigned* __restrict__ cnt,
                                               u64* __restrict__ keys) {
    const unsigned total = min(cnt[0], CAP);
    const int lane = threadIdx.x & 63;
    const unsigned w = (blockIdx.x * 256 + threadIdx.x) >> 6;
    const unsigned nw = gridDim.x * 4;
    for (unsigned i = w; i < total; i += nw) {
        const u64 e = cand[i];
        const unsigned pc = (unsigned)(e >> 32);
        const int p = pc >> 14, c = pc & 16383;
        if (s2f((unsigned)(e & 0xffffffffull)) < s2f(gmax[p]) - DELTA) continue;
        const float dinv = 1.0f / den[c];
        const float4 a = *(const float4*)(zf32 + (size_t)p * D + lane * 4);
        const float4 b = *(const float4*)(E + (size_t)c * D + lane * 4);
        float sv = fmaf(a.x, b.x * dinv, fmaf(a.y, b.y * dinv,
                   fmaf(a.z, b.z * dinv, a.w * (b.w * dinv))));
        #pragma unroll
        for (int o = 1; o < 64; o <<= 1) sv += __shfl_xor(sv, o);
        if (lane == 0)
            atomicMax(keys + p, ((u64)f2s(sv) << 32) | (unsigned)(16383 - c));
    }
}

// ---- gather + outputs ----
__global__ __launch_bounds__(256) void finalize(const float* __restrict__ E,
                                                const float* __restrict__ den,
                                                const u64* __restrict__ keys,
                                                float* __restrict__ out) {
    const int n = blockIdx.x, tid = threadIdx.x;
    const u64 key = keys[n];
    const int idx = 16383 - (int)(unsigned)(key & 0xffffffffull);
    const float v = E[(size_t)idx * D + tid] / den[idx];
    const int b = n >> 10, off = n & 1023;
    out[(size_t)(b * D + tid) * 1024 + off] = v;
    const float S = 5.65685424949238019520675489683895f;  // sqrt(32)
    out[O_BIT + (size_t)n * D + tid] = (float)((int)(v * S) + 4);
    if (tid == 0) out[O_IDX + n] = (float)idx;
    if (n == 0 && tid == 0) out[O_LOSS] = 0.0f;
}

extern "C" void kernel_launch(void* const* d_in, const int* in_sizes, int n_in,
                              void* d_out, int out_size, void* d_ws, size_t ws_size,
                              hipStream_t stream) {
    const float* z = (const float*)d_in[0];
    const float* E = (const float*)d_in[1];
    float* out = (float*)d_out;

    char* w = (char*)d_ws;
    u64*            cand = (u64*)w;             w += (size_t)CAP * 8;        // 12.8 MB
    unsigned short* ewb  = (unsigned short*)w;  w += (size_t)K * D * 2;      //  8 MB
    unsigned short* zfb  = (unsigned short*)w;  w += (size_t)NPTS * D * 2;   //  4 MB
    float*          zf32 = (float*)w;           w += (size_t)NPTS * D * 4;   //  8 MB
    u64*            keys = (u64*)w;             w += (size_t)NPTS * 8;       // 64 KB
    float*          den  = (float*)w;           w += (size_t)K * 4;          // 64 KB
    unsigned*       gmax = (unsigned*)w;        w += (size_t)NPTS * 4;       // 32 KB
    unsigned*       cnt  = (unsigned*)w;

    prep_codebook<<<K / 32, 256, 0, stream>>>(E, den, ewb, gmax, keys, cnt);
    prep_z<<<128, 256, 0, stream>>>(z, zfb, zf32);

    dim3 gpre(NPTS / 128, 16);          // codes [0, 2048)
    pre_score<<<gpre, 256, 0, stream>>>(zfb, ewb, gmax);

    dim3 gmain(NPTS / 128, K / 128);    // all codes
    score<<<gmain, 256, 0, stream>>>(zfb, ewb, gmax, cand, cnt);

    cand_max<<<256, 256, 0, stream>>>(cand, cnt, gmax);
    rescore<<<512, 256, 0, stream>>>(zf32, E, den, gmax, cand, cnt, keys);
    finalize<<<NPTS, 256, 0, stream>>>(E, den, keys, out);
}